// Round 16
// baseline (438.428 us; speedup 1.0000x reference)
//
#include <hip/hip_runtime.h>
#include <stdint.h>

#define N_ROWS 65536
#define K_DIM  1024
#define J_OUT  256
#define ROWS_PB 64        // rows per block
#define NT64 16           // K-steps of 64
#define THREADS 512       // 8 waves, each owns 64 fused cols x ALL 64 rows

typedef _Float16 half8 __attribute__((ext_vector_type(8)));
typedef _Float16 half4 __attribute__((ext_vector_type(4)));
typedef float    f32x4 __attribute__((ext_vector_type(4)));

// ---------------- threefry2x32, key=(0,42) — partitionable, XOR-fold -------
// bits = b1 ^ b2 of threefry2x32(k1=0,k2=42, x0=0, x1=i).  (Verified R5.)
__device__ __forceinline__ uint32_t rotl32(uint32_t v, uint32_t r) {
  return __builtin_amdgcn_alignbit(v, v, 32u - r);
}
__device__ __forceinline__ uint32_t tf_bits_xor(uint32_t ctr) {
  const uint32_t ks0 = 0u, ks1 = 42u, ks2 = 0x1BD11BF0u;
  uint32_t x0 = 0u;
  uint32_t x1 = ctr + ks1;
#define TF_R(rr) x0 += x1; x1 = rotl32(x1, rr) ^ x0;
  TF_R(13) TF_R(15) TF_R(26) TF_R(6)
  x0 += ks1; x1 += ks2 + 1u;
  TF_R(17) TF_R(29) TF_R(16) TF_R(24)
  x0 += ks2; x1 += ks0 + 2u;
  TF_R(13) TF_R(15) TF_R(26) TF_R(6)
  x0 += ks0; x1 += ks1 + 3u;
  TF_R(17) TF_R(29) TF_R(16) TF_R(24)
  x0 += ks1; x1 += ks2 + 4u;
  TF_R(13) TF_R(15) TF_R(26) TF_R(6)
  x0 += ks2; x1 += ks0 + 5u;
#undef TF_R
  return x0 ^ x1;
}

// uniform then sqrt(2)*erfinv (XLA Giles, cheap-log form).  (Verified R12.)
__device__ __forceinline__ float eps_from_bits(uint32_t bits) {
  float f = __uint_as_float((bits >> 9) | 0x3F800000u) - 1.0f;
  float u = fmaxf(-0.99999994f, f * 2.0f - 0.99999994f);
  float w = __builtin_amdgcn_logf((1.0f - u) * (1.0f + u)) * (-0.6931471805599453f);
  float t = w - 2.5f;
  float p = 2.81022636e-08f;
  p = fmaf(p, t, 3.43273939e-07f);
  p = fmaf(p, t, -3.5233877e-06f);
  p = fmaf(p, t, -4.39150654e-06f);
  p = fmaf(p, t, 0.00021858087f);
  p = fmaf(p, t, -0.00125372503f);
  p = fmaf(p, t, -0.00417768164f);
  p = fmaf(p, t, 0.246640727f);
  p = fmaf(p, t, 1.50140941f);
  if (w >= 5.0f) {                       // rare; execz-skipped for most waves
    float s = sqrtf(w) - 3.0f;
    float q = -0.000200214257f;
    q = fmaf(q, s, 0.000100950558f);
    q = fmaf(q, s, 0.00134934322f);
    q = fmaf(q, s, -0.00367342844f);
    q = fmaf(q, s, 0.00573950773f);
    q = fmaf(q, s, -0.0076224613f);
    q = fmaf(q, s, -0.00943887047f);
    q = fmaf(q, s, 1.00167406f);
    q = fmaf(q, s, 2.83297682f);
    p = q;
  }
  return 1.41421354f * (p * u);
}

// ---------------- W pre-pack: f32->f16, per-wave K64-contiguous fragments --
__global__ void pack_w_kernel(const float* __restrict__ Wmu,
                              const float* __restrict__ Wls,
                              _Float16* __restrict__ wt) {
  const int chunk = blockIdx.x * blockDim.x + threadIdx.x;  // 0..65535
  const int lane = chunk & 63;
  const int n  = (chunk >> 6) & 3;
  const int ks = (chunk >> 8) & 1;
  const int w  = (chunk >> 9) & 7;
  const int t  = chunk >> 12;
  const int k0 = t * 64 + ks * 32 + (lane >> 4) * 8;
  const int c  = w * 32 + (n >> 1) * 16 + (lane & 15);
  const float* W = (n & 1) ? Wls : Wmu;
  half8 v;
#pragma unroll
  for (int e = 0; e < 8; ++e) v[e] = (_Float16)W[(size_t)(k0 + e) * J_OUT + c];
  *(half8*)(wt + (size_t)chunk * 8) = v;
}

// barrier WITHOUT vmcnt drain: LDS ordered, global loads/stores stay in flight
#define KBARRIER() asm volatile("s_waitcnt lgkmcnt(0)\n\ts_barrier" ::: "memory")

// one software-pipelined K64 step (64-row A slab, 2 staging chunks/thread)
#define KSTEP(T, BC, BN, SA0, SA1)                                             \
  {                                                                            \
    const _Float16* Ar_ = Abuf + ((T) & 1) * (ROWS_PB * 80);                   \
    _Float16* Aw_ = Abuf + (((T) + 1) & 1) * (ROWS_PB * 80);                   \
    if ((T) + 1 < NT64) {                                                      \
      half4 h0_, h1_;                                                          \
      _Pragma("unroll") for (int e = 0; e < 4; ++e) {                          \
        h0_[e] = (_Float16)SA0[e]; h1_[e] = (_Float16)SA1[e];                  \
      }                                                                        \
      *(half4*)(Aw_ + swaddr) = h0_;                                           \
      *(half4*)(Aw_ + swaddr + 32 * 80) = h1_;                                 \
    }                                                                          \
    if ((T) + 3 < NT64) {                                                      \
      SA0 = *(const f32x4*)(sp0 + ((T) + 3) * 64);                             \
      SA1 = *(const f32x4*)(sp1 + ((T) + 3) * 64);                             \
    }                                                                          \
    if ((T) + 1 < NT64) {                                                      \
      const _Float16* bbn_ = bbase + (size_t)((T) + 1) * 32768;                \
      _Pragma("unroll") for (int i = 0; i < 8; ++i)                            \
        BN[i] = *(const half8*)(bbn_ + i * 512);                               \
    }                                                                          \
    __builtin_amdgcn_s_setprio(1);                                             \
    _Pragma("unroll") for (int ks = 0; ks < 2; ++ks) {                         \
      half8 af_[4];                                                            \
      _Pragma("unroll") for (int m = 0; m < 4; ++m)                            \
        af_[m] = *(const half8*)(Ar_ + arbase + m * 1280 + ks * 32);           \
      _Pragma("unroll") for (int m = 0; m < 4; ++m)                            \
        _Pragma("unroll") for (int n = 0; n < 4; ++n)                          \
          acc[m][n] = __builtin_amdgcn_mfma_f32_16x16x32_f16(                  \
              af_[m], BC[ks * 4 + n], acc[m][n], 0, 0, 0);                     \
    }                                                                          \
    __builtin_amdgcn_s_setprio(0);                                             \
    KBARRIER();                                                                \
  }

__global__ __launch_bounds__(THREADS, 4)
void fused_heads_kernel(const float* __restrict__ x,
                        const _Float16* __restrict__ wt,
                        const float* __restrict__ b_mu,
                        const float* __restrict__ b_ls,
                        float* __restrict__ out) {
  // union: K-loop A dbuf [2][64*80] halves (20 KiB) / epilogue 32x260 f32
  __shared__ __align__(16) unsigned char smem[32 * 260 * 4];   // 33.3 KiB
  _Float16* Abuf = (_Float16*)smem;
  float*    ebuf = (float*)smem;

  const int tid  = threadIdx.x;
  const int lane = tid & 63;
  const int w    = tid >> 6;        // wave 0..7 -> fused cols w*64..w*64+63
  const int rowbase = blockIdx.x * ROWS_PB;

  // staging: thread -> rows (tid>>4) and 32+(tid>>4), 4-float chunk tid&15
  const int srow = tid >> 4, skc = tid & 15;
  const float* sp0 = x + (size_t)(rowbase + srow) * K_DIM + skc * 4;
  const float* sp1 = sp0 + (size_t)32 * K_DIM;
  const int swaddr = srow * 80 + skc * 4;   // halves

  // A fragment read base: lane (r = lane&15, g = lane>>4), +m*16*80, +ks*32
  const int arbase = (lane & 15) * 80 + (lane >> 4) * 8;
  // B: per (t64, w) one contiguous 4096-half (8 KB) block
  const _Float16* bbase = wt + ((size_t)w << 12) + lane * 8;

  f32x4 acc[4][4] = {};

  // ---- prologue: slab0 -> LDS buf0; slabs 1,2 + B(0) in flight
  {
    const f32x4 s0 = *(const f32x4*)(sp0);
    const f32x4 s1 = *(const f32x4*)(sp1);
    half4 h0, h1;
#pragma unroll
    for (int e = 0; e < 4; ++e) { h0[e] = (_Float16)s0[e]; h1[e] = (_Float16)s1[e]; }
    *(half4*)(&Abuf[swaddr]) = h0;
    *(half4*)(&Abuf[swaddr + 32 * 80]) = h1;
  }
  f32x4 sAa0 = *(const f32x4*)(sp0 + 64),  sAa1 = *(const f32x4*)(sp1 + 64);
  f32x4 sAb0 = *(const f32x4*)(sp0 + 128), sAb1 = *(const f32x4*)(sp1 + 128);
  half8 bfA[8], bfB[8];
#pragma unroll
  for (int i = 0; i < 8; ++i) bfA[i] = *(const half8*)(bbase + i * 512);
  KBARRIER();

#pragma unroll
  for (int tt = 0; tt < 8; ++tt) {
    KSTEP(2 * tt,     bfA, bfB, sAa0, sAa1)
    KSTEP(2 * tt + 1, bfB, bfA, sAb0, sAb1)
  }

  // ---- epilogue: fold bias + s=exp(ls) into acc ONCE (1 transcendental per
  // element total), then 6 rounds (2 row-halves x 3 arrays) of 32-row LDS
  // transpose + nontemporal full-line f32x4 stores; lgkm-only barriers.
  float* out_mean = out;
  float* out_var  = out + (size_t)N_ROWS * J_OUT;
  float* out_z    = out + 2 * (size_t)N_ROWS * J_OUT;
  const int colq = lane & 15;
  const int g4   = (lane >> 4) * 4;

#pragma unroll
  for (int q = 0; q < 2; ++q) {
    const int c = w * 32 + q * 16 + colq;
    const float bm = b_mu[c];
    const float bl = b_ls[c];
#pragma unroll
    for (int m = 0; m < 4; ++m)
#pragma unroll
      for (int e = 0; e < 4; ++e) {
        acc[m][2 * q][e]     = acc[m][2 * q][e] + bm;              // mean
        acc[m][2 * q + 1][e] = __expf(acc[m][2 * q + 1][e] + bl);  // s = std
      }
  }

#pragma unroll
  for (int mm = 0; mm < 2; ++mm)            // row-half: rows mm*32..mm*32+31
#pragma unroll
    for (int arr = 0; arr < 3; ++arr) {
#pragma unroll
      for (int mh = 0; mh < 2; ++mh) {
        const int m = mm * 2 + mh;
#pragma unroll
        for (int q = 0; q < 2; ++q) {
          const int lcol = w * 32 + q * 16 + colq;
#pragma unroll
          for (int e = 0; e < 4; ++e) {
            const int lrow = mh * 16 + g4 + e;      // 0..31
            const float mean = acc[m][2 * q][e];
            const float s    = acc[m][2 * q + 1][e];
            float val;
            if (arr == 0) {
              val = mean;
            } else if (arr == 1) {
              val = s * s;                           // var = exp(2*ls)
            } else {
              const uint32_t ctr =
                  (uint32_t)((rowbase + m * 16 + g4 + e) * J_OUT + lcol);
              val = fmaf(s, eps_from_bits(tf_bits_xor(ctr)), mean);
            }
            ebuf[lrow * 260 + lcol] = val;
          }
        }
      }
      KBARRIER();
      float* oarr = (arr == 0) ? out_mean : (arr == 1) ? out_var : out_z;
#pragma unroll
      for (int i = 0; i < 4; ++i) {
        const int idx = i * THREADS + tid;        // 0..2047
        const int r  = idx >> 6;                  // 0..31
        const int c4 = idx & 63;                  // float4 index in row
        const f32x4 v = *(const f32x4*)(ebuf + r * 260 + c4 * 4);
        __builtin_nontemporal_store(
            v, (f32x4*)(oarr + (size_t)(rowbase + mm * 32 + r) * J_OUT + c4 * 4));
      }
      KBARRIER();
    }
}

extern "C" void kernel_launch(void* const* d_in, const int* in_sizes, int n_in,
                              void* d_out, int out_size, void* d_ws, size_t ws_size,
                              hipStream_t stream) {
  const float* x   = (const float*)d_in[0];
  const float* Wmu = (const float*)d_in[1];
  const float* bmu = (const float*)d_in[2];
  const float* Wls = (const float*)d_in[3];
  const float* bls = (const float*)d_in[4];
  float* out = (float*)d_out;
  _Float16* wt = (_Float16*)d_ws;   // 1 MiB scratch

  pack_w_kernel<<<256, 256, 0, stream>>>(Wmu, Wls, wt);
  fused_heads_kernel<<<N_ROWS / ROWS_PB, THREADS, 0, stream>>>(x, wt, bmu, bls, out);
}

// Round 17
// 162.252 us; speedup vs baseline: 2.7021x; 2.7021x over previous
//
#include <hip/hip_runtime.h>
#include <stdint.h>

#define N_ROWS 65536
#define K_DIM  1024
#define J_OUT  256
#define ROWS_PB 64        // rows per block
#define NT64 16           // K-steps of 64
#define THREADS 512       // 8 waves, each owns 64 fused cols x ALL 64 rows

typedef _Float16 half8 __attribute__((ext_vector_type(8)));
typedef _Float16 half4 __attribute__((ext_vector_type(4)));
typedef float    f32x4 __attribute__((ext_vector_type(4)));

// ---------------- threefry2x32, key=(0,42) — partitionable, XOR-fold -------
// bits = b1 ^ b2 of threefry2x32(k1=0,k2=42, x0=0, x1=i).  (Verified R5.)
__device__ __forceinline__ uint32_t rotl32(uint32_t v, uint32_t r) {
  return __builtin_amdgcn_alignbit(v, v, 32u - r);
}
__device__ __forceinline__ uint32_t tf_bits_xor(uint32_t ctr) {
  const uint32_t ks0 = 0u, ks1 = 42u, ks2 = 0x1BD11BF0u;
  uint32_t x0 = 0u;
  uint32_t x1 = ctr + ks1;
#define TF_R(rr) x0 += x1; x1 = rotl32(x1, rr) ^ x0;
  TF_R(13) TF_R(15) TF_R(26) TF_R(6)
  x0 += ks1; x1 += ks2 + 1u;
  TF_R(17) TF_R(29) TF_R(16) TF_R(24)
  x0 += ks2; x1 += ks0 + 2u;
  TF_R(13) TF_R(15) TF_R(26) TF_R(6)
  x0 += ks0; x1 += ks1 + 3u;
  TF_R(17) TF_R(29) TF_R(16) TF_R(24)
  x0 += ks1; x1 += ks2 + 4u;
  TF_R(13) TF_R(15) TF_R(26) TF_R(6)
  x0 += ks2; x1 += ks0 + 5u;
#undef TF_R
  return x0 ^ x1;
}

// uniform then sqrt(2)*erfinv (XLA Giles, cheap-log form).  (Verified R12.)
__device__ __forceinline__ float eps_from_bits(uint32_t bits) {
  float f = __uint_as_float((bits >> 9) | 0x3F800000u) - 1.0f;
  float u = fmaxf(-0.99999994f, f * 2.0f - 0.99999994f);
  float w = __builtin_amdgcn_logf((1.0f - u) * (1.0f + u)) * (-0.6931471805599453f);
  float t = w - 2.5f;
  float p = 2.81022636e-08f;
  p = fmaf(p, t, 3.43273939e-07f);
  p = fmaf(p, t, -3.5233877e-06f);
  p = fmaf(p, t, -4.39150654e-06f);
  p = fmaf(p, t, 0.00021858087f);
  p = fmaf(p, t, -0.00125372503f);
  p = fmaf(p, t, -0.00417768164f);
  p = fmaf(p, t, 0.246640727f);
  p = fmaf(p, t, 1.50140941f);
  if (w >= 5.0f) {                       // rare; execz-skipped for most waves
    float s = sqrtf(w) - 3.0f;
    float q = -0.000200214257f;
    q = fmaf(q, s, 0.000100950558f);
    q = fmaf(q, s, 0.00134934322f);
    q = fmaf(q, s, -0.00367342844f);
    q = fmaf(q, s, 0.00573950773f);
    q = fmaf(q, s, -0.0076224613f);
    q = fmaf(q, s, -0.00943887047f);
    q = fmaf(q, s, 1.00167406f);
    q = fmaf(q, s, 2.83297682f);
    p = q;
  }
  return 1.41421354f * (p * u);
}

// ---------------- W pre-pack: f32->f16, per-wave K64-contiguous fragments --
__global__ void pack_w_kernel(const float* __restrict__ Wmu,
                              const float* __restrict__ Wls,
                              _Float16* __restrict__ wt) {
  const int chunk = blockIdx.x * blockDim.x + threadIdx.x;  // 0..65535
  const int lane = chunk & 63;
  const int n  = (chunk >> 6) & 3;
  const int ks = (chunk >> 8) & 1;
  const int w  = (chunk >> 9) & 7;
  const int t  = chunk >> 12;
  const int k0 = t * 64 + ks * 32 + (lane >> 4) * 8;
  const int c  = w * 32 + (n >> 1) * 16 + (lane & 15);
  const float* W = (n & 1) ? Wls : Wmu;
  half8 v;
#pragma unroll
  for (int e = 0; e < 8; ++e) v[e] = (_Float16)W[(size_t)(k0 + e) * J_OUT + c];
  *(half8*)(wt + (size_t)chunk * 8) = v;
}

// barrier WITHOUT vmcnt drain: LDS ordered, global loads/stores stay in flight
#define KBARRIER() asm volatile("s_waitcnt lgkmcnt(0)\n\ts_barrier" ::: "memory")

// one software-pipelined K64 step (64-row A slab, 2 staging chunks/thread)
#define KSTEP(T, BC, BN, SA0, SA1)                                             \
  {                                                                            \
    const _Float16* Ar_ = Abuf + ((T) & 1) * (ROWS_PB * 80);                   \
    _Float16* Aw_ = Abuf + (((T) + 1) & 1) * (ROWS_PB * 80);                   \
    if ((T) + 1 < NT64) {                                                      \
      half4 h0_, h1_;                                                          \
      _Pragma("unroll") for (int e = 0; e < 4; ++e) {                          \
        h0_[e] = (_Float16)SA0[e]; h1_[e] = (_Float16)SA1[e];                  \
      }                                                                        \
      *(half4*)(Aw_ + swaddr) = h0_;                                           \
      *(half4*)(Aw_ + swaddr + 32 * 80) = h1_;                                 \
    }                                                                          \
    if ((T) + 3 < NT64) {                                                      \
      SA0 = *(const f32x4*)(sp0 + ((T) + 3) * 64);                             \
      SA1 = *(const f32x4*)(sp1 + ((T) + 3) * 64);                             \
    }                                                                          \
    if ((T) + 1 < NT64) {                                                      \
      const _Float16* bbn_ = bbase + (size_t)((T) + 1) * 32768;                \
      _Pragma("unroll") for (int i = 0; i < 8; ++i)                            \
        BN[i] = *(const half8*)(bbn_ + i * 512);                               \
    }                                                                          \
    _Pragma("unroll") for (int ks = 0; ks < 2; ++ks) {                         \
      half8 af_[4];                                                            \
      _Pragma("unroll") for (int m = 0; m < 4; ++m)                            \
        af_[m] = *(const half8*)(Ar_ + arbase + m * 1280 + ks * 32);           \
      _Pragma("unroll") for (int m = 0; m < 4; ++m)                            \
        _Pragma("unroll") for (int n = 0; n < 4; ++n)                          \
          acc[m][n] = __builtin_amdgcn_mfma_f32_16x16x32_f16(                  \
              af_[m], BC[ks * 4 + n], acc[m][n], 0, 0, 0);                     \
    }                                                                          \
    KBARRIER();                                                                \
  }

__global__ __launch_bounds__(THREADS, 4)
void fused_heads_kernel(const float* __restrict__ x,
                        const _Float16* __restrict__ wt,
                        const float* __restrict__ b_mu,
                        const float* __restrict__ b_ls,
                        float* __restrict__ out) {
  // union: K-loop A dbuf [2][64*80] halves (20 KiB) / epilogue 32x260 f32
  __shared__ __align__(16) unsigned char smem[32 * 260 * 4];   // 33.3 KiB
  _Float16* Abuf = (_Float16*)smem;
  float*    ebuf = (float*)smem;

  const int tid  = threadIdx.x;
  const int lane = tid & 63;
  const int w    = tid >> 6;        // wave 0..7 -> fused cols w*64..w*64+63
  const int rowbase = blockIdx.x * ROWS_PB;

  // staging: thread -> rows (tid>>4) and 32+(tid>>4), 4-float chunk tid&15
  const int srow = tid >> 4, skc = tid & 15;
  const float* sp0 = x + (size_t)(rowbase + srow) * K_DIM + skc * 4;
  const float* sp1 = sp0 + (size_t)32 * K_DIM;
  const int swaddr = srow * 80 + skc * 4;   // halves

  // A fragment read base: lane (r = lane&15, g = lane>>4), +m*16*80, +ks*32
  const int arbase = (lane & 15) * 80 + (lane >> 4) * 8;
  // B: per (t64, w) one contiguous 4096-half (8 KB) block
  const _Float16* bbase = wt + ((size_t)w << 12) + lane * 8;

  f32x4 acc[4][4] = {};

  // ---- prologue: slab0 -> LDS buf0; slabs 1,2 + B(0) in flight
  {
    const f32x4 s0 = *(const f32x4*)(sp0);
    const f32x4 s1 = *(const f32x4*)(sp1);
    half4 h0, h1;
#pragma unroll
    for (int e = 0; e < 4; ++e) { h0[e] = (_Float16)s0[e]; h1[e] = (_Float16)s1[e]; }
    *(half4*)(&Abuf[swaddr]) = h0;
    *(half4*)(&Abuf[swaddr + 32 * 80]) = h1;
  }
  f32x4 sAa0 = *(const f32x4*)(sp0 + 64),  sAa1 = *(const f32x4*)(sp1 + 64);
  f32x4 sAb0 = *(const f32x4*)(sp0 + 128), sAb1 = *(const f32x4*)(sp1 + 128);
  half8 bfA[8], bfB[8];
#pragma unroll
  for (int i = 0; i < 8; ++i) bfA[i] = *(const half8*)(bbase + i * 512);
  KBARRIER();

#pragma unroll
  for (int tt = 0; tt < 8; ++tt) {
    KSTEP(2 * tt,     bfA, bfB, sAa0, sAa1)
    KSTEP(2 * tt + 1, bfB, bfA, sAb0, sAb1)
  }

  // ---- epilogue: fold bias + s=exp(ls) into acc ONCE (1 transcendental per
  // element total), then 6 rounds (2 row-halves x 3 arrays) of 32-row LDS
  // transpose + plain full-line f32x4 stores; lgkm-only barriers.
  float* out_mean = out;
  float* out_var  = out + (size_t)N_ROWS * J_OUT;
  float* out_z    = out + 2 * (size_t)N_ROWS * J_OUT;
  const int colq = lane & 15;
  const int g4   = (lane >> 4) * 4;

#pragma unroll
  for (int q = 0; q < 2; ++q) {
    const int c = w * 32 + q * 16 + colq;
    const float bm = b_mu[c];
    const float bl = b_ls[c];
#pragma unroll
    for (int m = 0; m < 4; ++m)
#pragma unroll
      for (int e = 0; e < 4; ++e) {
        acc[m][2 * q][e]     = acc[m][2 * q][e] + bm;              // mean
        acc[m][2 * q + 1][e] = __expf(acc[m][2 * q + 1][e] + bl);  // s = std
      }
  }

#pragma unroll
  for (int mm = 0; mm < 2; ++mm)            // row-half: rows mm*32..mm*32+31
#pragma unroll
    for (int arr = 0; arr < 3; ++arr) {
#pragma unroll
      for (int mh = 0; mh < 2; ++mh) {
        const int m = mm * 2 + mh;
#pragma unroll
        for (int q = 0; q < 2; ++q) {
          const int lcol = w * 32 + q * 16 + colq;
#pragma unroll
          for (int e = 0; e < 4; ++e) {
            const int lrow = mh * 16 + g4 + e;      // 0..31
            const float mean = acc[m][2 * q][e];
            const float s    = acc[m][2 * q + 1][e];
            float val;
            if (arr == 0) {
              val = mean;
            } else if (arr == 1) {
              val = s * s;                           // var = exp(2*ls)
            } else {
              const uint32_t ctr =
                  (uint32_t)((rowbase + m * 16 + g4 + e) * J_OUT + lcol);
              val = fmaf(s, eps_from_bits(tf_bits_xor(ctr)), mean);
            }
            ebuf[lrow * 260 + lcol] = val;
          }
        }
      }
      KBARRIER();
      float* oarr = (arr == 0) ? out_mean : (arr == 1) ? out_var : out_z;
#pragma unroll
      for (int i = 0; i < 4; ++i) {
        const int idx = i * THREADS + tid;        // 0..2047
        const int r  = idx >> 6;                  // 0..31
        const int c4 = idx & 63;                  // float4 index in row
        const f32x4 v = *(const f32x4*)(ebuf + r * 260 + c4 * 4);
        *(f32x4*)(oarr + (size_t)(rowbase + mm * 32 + r) * J_OUT + c4 * 4) = v;
      }
      KBARRIER();
    }
}

extern "C" void kernel_launch(void* const* d_in, const int* in_sizes, int n_in,
                              void* d_out, int out_size, void* d_ws, size_t ws_size,
                              hipStream_t stream) {
  const float* x   = (const float*)d_in[0];
  const float* Wmu = (const float*)d_in[1];
  const float* bmu = (const float*)d_in[2];
  const float* Wls = (const float*)d_in[3];
  const float* bls = (const float*)d_in[4];
  float* out = (float*)d_out;
  _Float16* wt = (_Float16*)d_ws;   // 1 MiB scratch

  pack_w_kernel<<<256, 256, 0, stream>>>(Wmu, Wls, wt);
  fused_heads_kernel<<<N_ROWS / ROWS_PB, THREADS, 0, stream>>>(x, wt, bmu, bls, out);
}